// Round 23
// baseline (1153.998 us; speedup 1.0000x reference)
//
#include <hip/hip_runtime.h>

// SNN layer: B=8, S=1024, I=512, H=1024, O=512, T=8
// Verified numerics (R22 PASS, absmax=0): BLIS/AOCL kc=512 sgemm emulation:
//   K=512  -> single sequential ascending-k fused-FMA chain
//   K=1024 -> chains [0,512)+[512,1024), delta = ch0 + ch1
//   LIF: mem += c; spike = mem>0.5; fired -> 0.0. Layer2: (mem+delta)+b2.
// R23: perf — 128x128 tile, 8x8 microtile (64 FMA per 4 ds_read_b128 per k,
// vs 16:2 before). Same accumulation order per output element.
static constexpr int B_ = 8, S_ = 1024, I_ = 512, H_ = 1024, O_ = 512, T_ = 8;
static constexpr int M_ = B_ * S_;
static constexpr float TH = 0.5f;

// ---------------------------------------------------------------------------
// K1: inp_cur = dot(x, w1^T) + b1 (full-K single chain) -> 8-step LIF ->
// bit-packed spikes. 128x128 tile, 256 threads, 8x8/thread, BK=16.
// ---------------------------------------------------------------------------
__global__ __launch_bounds__(256) void k1(const float* __restrict__ X,
                                          const float* __restrict__ W1,
                                          const float* __restrict__ B1,
                                          unsigned char* __restrict__ SPB) {
  __shared__ float As[16][132];
  __shared__ float Bs[16][132];
  const int tid = threadIdx.x;
  const int tx = tid & 15, ty = tid >> 4;
  const int rowBase = blockIdx.x * 128, colBase = blockIdx.y * 128;

  float acc[8][8];
#pragma unroll
  for (int i = 0; i < 8; ++i)
#pragma unroll
    for (int j = 0; j < 8; ++j) acc[i][j] = 0.f;

  for (int it = 0; it < 32; ++it) {
#pragma unroll
    for (int l = 0; l < 2; ++l) {
      int f = tid + l * 256;
      int rr = f >> 2;          // 0..127
      int kq = (f & 3) << 2;    // 0,4,8,12
      float4 va = *(const float4*)&X[(size_t)(rowBase + rr) * I_ + it * 16 + kq];
      As[kq + 0][rr] = va.x; As[kq + 1][rr] = va.y;
      As[kq + 2][rr] = va.z; As[kq + 3][rr] = va.w;
      float4 vb = *(const float4*)&W1[(size_t)(colBase + rr) * I_ + it * 16 + kq];
      Bs[kq + 0][rr] = vb.x; Bs[kq + 1][rr] = vb.y;
      Bs[kq + 2][rr] = vb.z; Bs[kq + 3][rr] = vb.w;
    }
    __syncthreads();
#pragma unroll
    for (int k = 0; k < 16; ++k) {
      float a[8], b[8];
      *(float4*)&a[0] = *(const float4*)&As[k][ty * 8];
      *(float4*)&a[4] = *(const float4*)&As[k][ty * 8 + 4];
      *(float4*)&b[0] = *(const float4*)&Bs[k][tx * 8];
      *(float4*)&b[4] = *(const float4*)&Bs[k][tx * 8 + 4];
#pragma unroll
      for (int i = 0; i < 8; ++i)
#pragma unroll
        for (int j = 0; j < 8; ++j) acc[i][j] = fmaf(a[i], b[j], acc[i][j]);
    }
    __syncthreads();
  }

#pragma unroll
  for (int i = 0; i < 8; ++i) {
    int row = rowBase + ty * 8 + i;
    unsigned char by[8];
#pragma unroll
    for (int j = 0; j < 8; ++j) {
      int col = colBase + tx * 8 + j;
      float c = acc[i][j] + B1[col];  // single chain + b1
      float m = 0.f;
      unsigned bits = 0;
#pragma unroll
      for (int t = 0; t < 8; ++t) {
        m = m + c;
        bool s = m > TH;
        bits |= (s ? 1u : 0u) << t;
        m = s ? 0.f : m;
      }
      by[j] = (unsigned char)bits;
    }
    uint2 pk;
    pk.x = (unsigned)by[0] | ((unsigned)by[1] << 8) | ((unsigned)by[2] << 16) |
           ((unsigned)by[3] << 24);
    pk.y = (unsigned)by[4] | ((unsigned)by[5] << 8) | ((unsigned)by[6] << 16) |
           ((unsigned)by[7] << 24);
    *(uint2*)&SPB[(size_t)row * H_ + colBase + tx * 8] = pk;
  }
}

// ---------------------------------------------------------------------------
// K2 (per step t): delta = dot(spike_t, w2^T), chains [512,512] joined at
// tile 32 (k=512), delta = ch0+ch1; mm = (mem_prev + delta) + b2; spikes ->
// out slice t; next mem stashed in out slice t+1. 128x128 tile, 8x8/thread.
// ---------------------------------------------------------------------------
__global__ __launch_bounds__(256) void k2(const unsigned char* __restrict__ SP,
                                          const float* __restrict__ W2,
                                          const float* __restrict__ B2,
                                          float* __restrict__ out, int t) {
  __shared__ float As[16][132];
  __shared__ float Bs[16][132];
  const int tid = threadIdx.x;
  const int tx = tid & 15, ty = tid >> 4;
  const int rowBase = blockIdx.x * 128, colBase = blockIdx.y * 128;

  float tot[8][8], cur[8][8];
#pragma unroll
  for (int i = 0; i < 8; ++i)
#pragma unroll
    for (int j = 0; j < 8; ++j) { tot[i][j] = 0.f; cur[i][j] = 0.f; }

  for (int it = 0; it < 64; ++it) {
    if (it == 32) {  // chunk boundary k=512: join, restart chain
#pragma unroll
      for (int i = 0; i < 8; ++i)
#pragma unroll
        for (int j = 0; j < 8; ++j) { tot[i][j] += cur[i][j]; cur[i][j] = 0.f; }
    }
#pragma unroll
    for (int l = 0; l < 2; ++l) {
      int f = tid + l * 256;
      int rr = f >> 2;          // 0..127
      int bq = (f & 3) << 2;    // byte offset 0,4,8,12
      unsigned u = *(const unsigned*)&SP[(size_t)(rowBase + rr) * H_ + it * 16 + bq];
      As[bq + 0][rr] = (float)((u >> t) & 1u);
      As[bq + 1][rr] = (float)((u >> (8 + t)) & 1u);
      As[bq + 2][rr] = (float)((u >> (16 + t)) & 1u);
      As[bq + 3][rr] = (float)((u >> (24 + t)) & 1u);
      float4 vb = *(const float4*)&W2[(size_t)(colBase + rr) * H_ + it * 16 + bq];
      Bs[bq + 0][rr] = vb.x; Bs[bq + 1][rr] = vb.y;
      Bs[bq + 2][rr] = vb.z; Bs[bq + 3][rr] = vb.w;
    }
    __syncthreads();
#pragma unroll
    for (int k = 0; k < 16; ++k) {
      float a[8], b[8];
      *(float4*)&a[0] = *(const float4*)&As[k][ty * 8];
      *(float4*)&a[4] = *(const float4*)&As[k][ty * 8 + 4];
      *(float4*)&b[0] = *(const float4*)&Bs[k][tx * 8];
      *(float4*)&b[4] = *(const float4*)&Bs[k][tx * 8 + 4];
#pragma unroll
      for (int i = 0; i < 8; ++i)
#pragma unroll
        for (int j = 0; j < 8; ++j) cur[i][j] = fmaf(a[i], b[j], cur[i][j]);
    }
    __syncthreads();
  }

  const int col0 = colBase + tx * 8;
  float4 b2a = *(const float4*)&B2[col0];
  float4 b2b = *(const float4*)&B2[col0 + 4];
#pragma unroll
  for (int i = 0; i < 8; ++i) {
    int row = rowBase + ty * 8 + i;
    int bb = row >> 10;          // row / S_
    int ss = row & (S_ - 1);
    size_t slot_t = (((size_t)bb * T_ + t) * S_ + ss) * O_ + col0;
    float4 mp0, mp1;
    if (t == 0) {
      mp0 = make_float4(0.f, 0.f, 0.f, 0.f);
      mp1 = make_float4(0.f, 0.f, 0.f, 0.f);
    } else {
      mp0 = *(const float4*)&out[slot_t];
      mp1 = *(const float4*)&out[slot_t + 4];
    }
    float mm[8];
#pragma unroll
    for (int j = 0; j < 4; ++j) {
      float d = tot[i][j] + cur[i][j];            // ch0 + ch1
      mm[j] = ((&mp0.x)[j] + d) + (&b2a.x)[j];    // (mem2 + delta) + b2
    }
#pragma unroll
    for (int j = 0; j < 4; ++j) {
      float d = tot[i][j + 4] + cur[i][j + 4];
      mm[j + 4] = ((&mp1.x)[j] + d) + (&b2b.x)[j];
    }
    float4 sp0, sp1, mn0, mn1;
#pragma unroll
    for (int j = 0; j < 4; ++j) {
      bool s = mm[j] > TH;
      (&sp0.x)[j] = s ? 1.f : 0.f;
      (&mn0.x)[j] = s ? 0.f : mm[j];
      bool s2 = mm[j + 4] > TH;
      (&sp1.x)[j] = s2 ? 1.f : 0.f;
      (&mn1.x)[j] = s2 ? 0.f : mm[j + 4];
    }
    *(float4*)&out[slot_t] = sp0;
    *(float4*)&out[slot_t + 4] = sp1;
    if (t < T_ - 1) {
      size_t slot_n = (((size_t)bb * T_ + (t + 1)) * S_ + ss) * O_ + col0;
      *(float4*)&out[slot_n] = mn0;
      *(float4*)&out[slot_n + 4] = mn1;
    }
  }
}

extern "C" void kernel_launch(void* const* d_in, const int* in_sizes, int n_in,
                              void* d_out, int out_size, void* d_ws, size_t ws_size,
                              hipStream_t stream) {
  const float* x  = (const float*)d_in[0];   // (B,S,I)
  const float* w1 = (const float*)d_in[1];   // (H,I)
  const float* b1 = (const float*)d_in[2];   // (H)
  const float* w2 = (const float*)d_in[3];   // (O,H)
  const float* b2 = (const float*)d_in[4];   // (O)
  float* out = (float*)d_out;                // (B,T,S,O) f32

  unsigned char* spikeB = (unsigned char*)d_ws;  // M*H bytes = 8.4 MB

  k1<<<dim3(M_ / 128, H_ / 128), 256, 0, stream>>>(x, w1, b1, spikeB);
  for (int t = 0; t < T_; ++t)
    k2<<<dim3(M_ / 128, O_ / 128), 256, 0, stream>>>(spikeB, w2, b2, out, t);
}

// Round 24
// 982.588 us; speedup vs baseline: 1.1744x; 1.1744x over previous
//
#include <hip/hip_runtime.h>

// SNN layer: B=8, S=1024, I=512, H=1024, O=512, T=8
// Verified numerics (R22 PASS, absmax=0): BLIS/AOCL kc=512 sgemm emulation:
//   K=512  -> single sequential ascending-k fused-FMA chain
//   K=1024 -> chains [0,512)+[512,1024), delta = ch0 + ch1 (one join add)
//   LIF: mem += c; spike = mem>0.5; fired -> 0.0. Layer2: (mem+delta)+b2.
// R24 perf: k1 = 128x64 tile / 8x4 micro (grid 1024, 4 blk/CU);
//           k2 = 64x64 tile / 4x4 micro, BOTH K-chunks processed
//           concurrently (2x ILP, half the barriers), grid 1024.
static constexpr int B_ = 8, S_ = 1024, I_ = 512, H_ = 1024, O_ = 512, T_ = 8;
static constexpr int M_ = B_ * S_;
static constexpr float TH = 0.5f;

// ---------------------------------------------------------------------------
// K1: inp_cur = dot(x, w1^T) + b1 (full-K single chain) -> 8-step LIF ->
// bit-packed spikes. 128x64 tile, 256 threads, 8x4/thread, BK=16.
// ---------------------------------------------------------------------------
__global__ __launch_bounds__(256) void k1(const float* __restrict__ X,
                                          const float* __restrict__ W1,
                                          const float* __restrict__ B1,
                                          unsigned char* __restrict__ SPB) {
  __shared__ float As[16][132];   // 128 rows (+pad)
  __shared__ float Bs[16][68];    // 64 cols  (+pad)
  const int tid = threadIdx.x;
  const int tx = tid & 15, ty = tid >> 4;   // ty: 16 row-groups of 8
  const int rowBase = blockIdx.x * 128, colBase = blockIdx.y * 64;

  float acc[8][4];
#pragma unroll
  for (int i = 0; i < 8; ++i)
#pragma unroll
    for (int j = 0; j < 4; ++j) acc[i][j] = 0.f;

  for (int it = 0; it < 32; ++it) {
    // stage A: 128x16 floats (512 float4, 2/thread)
#pragma unroll
    for (int l = 0; l < 2; ++l) {
      int f = tid + l * 256;
      int rr = f >> 2, kq = (f & 3) << 2;
      float4 va = *(const float4*)&X[(size_t)(rowBase + rr) * I_ + it * 16 + kq];
      As[kq + 0][rr] = va.x; As[kq + 1][rr] = va.y;
      As[kq + 2][rr] = va.z; As[kq + 3][rr] = va.w;
    }
    // stage B: 64x16 floats (256 float4, 1/thread)
    {
      int rr = tid >> 2, kq = (tid & 3) << 2;
      float4 vb = *(const float4*)&W1[(size_t)(colBase + rr) * I_ + it * 16 + kq];
      Bs[kq + 0][rr] = vb.x; Bs[kq + 1][rr] = vb.y;
      Bs[kq + 2][rr] = vb.z; Bs[kq + 3][rr] = vb.w;
    }
    __syncthreads();
#pragma unroll
    for (int k = 0; k < 16; ++k) {
      float a[8], b[4];
      *(float4*)&a[0] = *(const float4*)&As[k][ty * 8];
      *(float4*)&a[4] = *(const float4*)&As[k][ty * 8 + 4];
      *(float4*)&b[0] = *(const float4*)&Bs[k][tx * 4];
#pragma unroll
      for (int i = 0; i < 8; ++i)
#pragma unroll
        for (int j = 0; j < 4; ++j) acc[i][j] = fmaf(a[i], b[j], acc[i][j]);
    }
    __syncthreads();
  }

#pragma unroll
  for (int i = 0; i < 8; ++i) {
    int row = rowBase + ty * 8 + i;
    unsigned char by[4];
#pragma unroll
    for (int j = 0; j < 4; ++j) {
      int col = colBase + tx * 4 + j;
      float c = acc[i][j] + B1[col];  // single chain + b1
      float m = 0.f;
      unsigned bits = 0;
#pragma unroll
      for (int t = 0; t < 8; ++t) {
        m = m + c;
        bool s = m > TH;
        bits |= (s ? 1u : 0u) << t;
        m = s ? 0.f : m;
      }
      by[j] = (unsigned char)bits;
    }
    uchar4 pk; pk.x = by[0]; pk.y = by[1]; pk.z = by[2]; pk.w = by[3];
    *(uchar4*)&SPB[(size_t)row * H_ + colBase + tx * 4] = pk;
  }
}

// ---------------------------------------------------------------------------
// K2 (per step t): delta = dot(spike_t, w2^T), two independent chains
// processed CONCURRENTLY (cur0: k in [0,512), cur1: k in [512,1024)),
// delta = cur0 + cur1; mm = (mem_prev + delta) + b2; spikes -> out slice t;
// next mem stashed in out slice t+1. 64x64 tile, 4x4/thread, 32 its.
// ---------------------------------------------------------------------------
__global__ __launch_bounds__(256) void k2(const unsigned char* __restrict__ SP,
                                          const float* __restrict__ W2,
                                          const float* __restrict__ B2,
                                          float* __restrict__ out, int t) {
  __shared__ float As0[16][68];
  __shared__ float As1[16][68];
  __shared__ float Bs0[16][68];
  __shared__ float Bs1[16][68];
  const int tid = threadIdx.x;
  const int tx = tid & 15, ty = tid >> 4;
  const int rowBase = blockIdx.x * 64, colBase = blockIdx.y * 64;

  float cur0[4][4], cur1[4][4];
#pragma unroll
  for (int i = 0; i < 4; ++i)
#pragma unroll
    for (int j = 0; j < 4; ++j) { cur0[i][j] = 0.f; cur1[i][j] = 0.f; }

  for (int it = 0; it < 32; ++it) {
    {
      int rr = tid >> 2, bq = (tid & 3) << 2;
      // A0: spikes k = it*16 .. ; A1: k = 512 + it*16 ..
      unsigned u0 = *(const unsigned*)&SP[(size_t)(rowBase + rr) * H_ + it * 16 + bq];
      As0[bq + 0][rr] = (float)((u0 >> t) & 1u);
      As0[bq + 1][rr] = (float)((u0 >> (8 + t)) & 1u);
      As0[bq + 2][rr] = (float)((u0 >> (16 + t)) & 1u);
      As0[bq + 3][rr] = (float)((u0 >> (24 + t)) & 1u);
      unsigned u1 = *(const unsigned*)&SP[(size_t)(rowBase + rr) * H_ + 512 + it * 16 + bq];
      As1[bq + 0][rr] = (float)((u1 >> t) & 1u);
      As1[bq + 1][rr] = (float)((u1 >> (8 + t)) & 1u);
      As1[bq + 2][rr] = (float)((u1 >> (16 + t)) & 1u);
      As1[bq + 3][rr] = (float)((u1 >> (24 + t)) & 1u);
      float4 vb0 = *(const float4*)&W2[(size_t)(colBase + rr) * H_ + it * 16 + bq];
      Bs0[bq + 0][rr] = vb0.x; Bs0[bq + 1][rr] = vb0.y;
      Bs0[bq + 2][rr] = vb0.z; Bs0[bq + 3][rr] = vb0.w;
      float4 vb1 = *(const float4*)&W2[(size_t)(colBase + rr) * H_ + 512 + it * 16 + bq];
      Bs1[bq + 0][rr] = vb1.x; Bs1[bq + 1][rr] = vb1.y;
      Bs1[bq + 2][rr] = vb1.z; Bs1[bq + 3][rr] = vb1.w;
    }
    __syncthreads();
#pragma unroll
    for (int k = 0; k < 16; ++k) {
      float a0[4], b0[4], a1[4], b1v[4];
      *(float4*)&a0[0] = *(const float4*)&As0[k][ty * 4];
      *(float4*)&b0[0] = *(const float4*)&Bs0[k][tx * 4];
      *(float4*)&a1[0] = *(const float4*)&As1[k][ty * 4];
      *(float4*)&b1v[0] = *(const float4*)&Bs1[k][tx * 4];
#pragma unroll
      for (int i = 0; i < 4; ++i)
#pragma unroll
        for (int j = 0; j < 4; ++j) {
          cur0[i][j] = fmaf(a0[i], b0[j], cur0[i][j]);
          cur1[i][j] = fmaf(a1[i], b1v[j], cur1[i][j]);
        }
    }
    __syncthreads();
  }

  const int col0 = colBase + tx * 4;
  float4 b2v = *(const float4*)&B2[col0];
#pragma unroll
  for (int i = 0; i < 4; ++i) {
    int row = rowBase + ty * 4 + i;
    int bb = row >> 10;          // row / S_
    int ss = row & (S_ - 1);
    size_t slot_t = (((size_t)bb * T_ + t) * S_ + ss) * O_ + col0;
    float4 mp;
    if (t == 0) mp = make_float4(0.f, 0.f, 0.f, 0.f);
    else mp = *(const float4*)&out[slot_t];  // state stashed by step t-1
    float d[4], mm[4];
#pragma unroll
    for (int j = 0; j < 4; ++j)
      d[j] = cur0[i][j] + cur1[i][j];        // ch0 + ch1 (single join add)
    mm[0] = (mp.x + d[0]) + b2v.x;           // (mem2 + delta) + b2
    mm[1] = (mp.y + d[1]) + b2v.y;
    mm[2] = (mp.z + d[2]) + b2v.z;
    mm[3] = (mp.w + d[3]) + b2v.w;
    float4 sp, mn;
    sp.x = (mm[0] > TH) ? 1.f : 0.f;  mn.x = (mm[0] > TH) ? 0.f : mm[0];
    sp.y = (mm[1] > TH) ? 1.f : 0.f;  mn.y = (mm[1] > TH) ? 0.f : mm[1];
    sp.z = (mm[2] > TH) ? 1.f : 0.f;  mn.z = (mm[2] > TH) ? 0.f : mm[2];
    sp.w = (mm[3] > TH) ? 1.f : 0.f;  mn.w = (mm[3] > TH) ? 0.f : mm[3];
    *(float4*)&out[slot_t] = sp;      // final spikes for step t
    if (t < T_ - 1) {
      size_t slot_n = (((size_t)bb * T_ + (t + 1)) * S_ + ss) * O_ + col0;
      *(float4*)&out[slot_n] = mn;    // stash state; overwritten at t+1
    }
  }
}

extern "C" void kernel_launch(void* const* d_in, const int* in_sizes, int n_in,
                              void* d_out, int out_size, void* d_ws, size_t ws_size,
                              hipStream_t stream) {
  const float* x  = (const float*)d_in[0];   // (B,S,I)
  const float* w1 = (const float*)d_in[1];   // (H,I)
  const float* b1 = (const float*)d_in[2];   // (H)
  const float* w2 = (const float*)d_in[3];   // (O,H)
  const float* b2 = (const float*)d_in[4];   // (O)
  float* out = (float*)d_out;                // (B,T,S,O) f32

  unsigned char* spikeB = (unsigned char*)d_ws;  // M*H bytes = 8.4 MB

  k1<<<dim3(M_ / 128, H_ / 64), 256, 0, stream>>>(x, w1, b1, spikeB);
  for (int t = 0; t < T_; ++t)
    k2<<<dim3(M_ / 64, O_ / 64), 256, 0, stream>>>(spikeB, w2, b2, out, t);
}